// Round 1
// baseline (131.067 us; speedup 1.0000x reference)
//
#include <hip/hip_runtime.h>
#include <math.h>

#define kB 4
#define kM 4096
#define kN (kB * kM)
#define kPadF -999.0f
#define kPadI -999
#define kCutoff 7.0f
#define kRowsPerBlock 64

// ---------------------------------------------------------------------------
// Kernel 1: per-atom outputs — dihedral angle (col 0) + partner coords (2..7)
// ---------------------------------------------------------------------------
__global__ __launch_bounds__(256)
void per_atom_kernel(const float* __restrict__ coords,   // (B,M,3)
                     const int*   __restrict__ cidx,     // (N,)
                     const int*   __restrict__ partners, // (N,2)
                     const int*   __restrict__ aidx,     // (N,4)
                     float*       __restrict__ out)      // (N,8)
{
    int i = blockIdx.x * 256 + threadIdx.x;
    if (i >= kN) return;
    int b = i >> 12;  // atom_batch = i // M, M = 4096

    // ---- partners (cols 2..7) ----
    float o2, o3, o4, o5, o6, o7;
    int p0 = partners[2 * i + 0];
    int p1 = partners[2 * i + 1];
    if (p0 == kPadI) { o2 = o3 = o4 = kPadF; }
    else {
        const float* s = coords + (size_t)(b * kM + p0) * 3;
        o2 = s[0]; o3 = s[1]; o4 = s[2];
    }
    if (p1 == kPadI) { o5 = o6 = o7 = kPadF; }
    else {
        const float* s = coords + (size_t)(b * kM + p1) * 3;
        o5 = s[0]; o6 = s[1]; o7 = s[2];
    }

    // ---- dihedral (col 0) ----
    int4 a = *reinterpret_cast<const int4*>(aidx + 4 * i);
    float ang = kPadF;
    if (a.x != kPadI && a.y != kPadI && a.z != kPadI && a.w != kPadI) {
        int ai[4] = {a.x, a.y, a.z, a.w};
        float P[4][3];
        #pragma unroll
        for (int k = 0; k < 4; ++k) {
            int g  = ai[k];
            int gb = g >> 12;          // batch of gathered atom
            int gc = cidx[g];          // its coordinate index
            const float* s = coords + (size_t)(gb * kM + gc) * 3;
            P[k][0] = s[0]; P[k][1] = s[1]; P[k][2] = s[2];
        }
        float b1x = P[1][0] - P[0][0], b1y = P[1][1] - P[0][1], b1z = P[1][2] - P[0][2];
        float b2x = P[2][0] - P[1][0], b2y = P[2][1] - P[1][1], b2z = P[2][2] - P[1][2];
        float b3x = P[3][0] - P[2][0], b3y = P[3][1] - P[2][1], b3z = P[3][2] - P[2][2];
        // n1 = b1 x b2 ; n2 = b2 x b3
        float n1x = b1y * b2z - b1z * b2y;
        float n1y = b1z * b2x - b1x * b2z;
        float n1z = b1x * b2y - b1y * b2x;
        float n2x = b2y * b3z - b2z * b3y;
        float n2y = b2z * b3x - b2x * b3z;
        float n2z = b2x * b3y - b2y * b3x;
        // b2n = b2 / (|b2| + 1e-12)
        float nb2 = sqrtf(b2x * b2x + b2y * b2y + b2z * b2z) + 1e-12f;
        float inv = 1.0f / nb2;
        float ux = b2x * inv, uy = b2y * inv, uz = b2z * inv;
        // m1 = n1 x b2n
        float m1x = n1y * uz - n1z * uy;
        float m1y = n1z * ux - n1x * uz;
        float m1z = n1x * uy - n1y * ux;
        float x = n1x * n2x + n1y * n2y + n1z * n2z;
        float y = m1x * n2x + m1y * n2y + m1z * n2z;
        ang = atan2f(y, x);
    }

    float* o = out + (size_t)i * 8;
    o[0] = ang;
    o[2] = o2; o[3] = o3; o[4] = o4;
    o[5] = o5; o[6] = o6; o[7] = o7;
}

// ---------------------------------------------------------------------------
// Kernel 2: masked pairwise-distance row sums (col 1).
// One block = 64 rows of one batch; whole batch's gathered coords in LDS.
// 4 threads per row, each scans M/4 columns; quad shuffle-reduce.
// ---------------------------------------------------------------------------
__global__ __launch_bounds__(256)
void nbr_kernel(const float* __restrict__ coords,  // (B,M,3)
                const int*   __restrict__ cidx,    // (N,)
                float*       __restrict__ out)     // (N,8)
{
    __shared__ float4 sc[kM];  // x, y, z, x^2+y^2+z^2  (64 KiB)

    const int blocksPerBatch = kM / kRowsPerBlock;  // 64
    int b    = blockIdx.x / blocksPerBatch;
    int row0 = (blockIdx.x % blocksPerBatch) * kRowsPerBlock;

    // stage the gathered batch coords into LDS
    for (int j = threadIdx.x; j < kM; j += 256) {
        int idx = cidx[b * kM + j];
        const float* s = coords + (size_t)(b * kM + idx) * 3;
        float x = s[0], y = s[1], z = s[2];
        sc[j] = make_float4(x, y, z, x * x + y * y + z * z);
    }
    __syncthreads();

    int r   = row0 + (threadIdx.x >> 2);
    int sub = threadIdx.x & 3;
    float4 ci = sc[r];

    float sum = 0.0f;
    #pragma unroll 8
    for (int jj = 0; jj < kM / 4; ++jj) {
        float4 c = sc[4 * jj + sub];
        float dot  = ci.x * c.x + ci.y * c.y + ci.z * c.z;
        float d2   = ci.w + c.w - 2.0f * dot;       // gram formula, same as ref
        float dist = sqrtf(fmaxf(d2, 0.0f) + 1e-12f);
        if (c.x != kPadF && dist <= kCutoff) sum += dist;
    }
    // reduce across the quad (lanes tid^1, tid^2 are the same row)
    sum += __shfl_xor(sum, 1);
    sum += __shfl_xor(sum, 2);
    if (sub == 0) {
        out[(size_t)(b * kM + r) * 8 + 1] = (ci.x != kPadF) ? sum : 0.0f;
    }
}

// ---------------------------------------------------------------------------
extern "C" void kernel_launch(void* const* d_in, const int* in_sizes, int n_in,
                              void* d_out, int out_size, void* d_ws, size_t ws_size,
                              hipStream_t stream) {
    const float* coords   = (const float*)d_in[0];  // (B,M,3) f32
    // d_in[1] = atom_batch (N,) == arange(N)//M — recomputed as i>>12
    const int*   cidx     = (const int*)d_in[2];    // (N,)
    const int*   partners = (const int*)d_in[3];    // (N,2)
    const int*   aidx     = (const int*)d_in[4];    // (N,4)
    float*       out      = (float*)d_out;          // (N,8)

    hipLaunchKernelGGL(per_atom_kernel, dim3(kN / 256), dim3(256), 0, stream,
                       coords, cidx, partners, aidx, out);
    hipLaunchKernelGGL(nbr_kernel, dim3(kB * (kM / kRowsPerBlock)), dim3(256), 0, stream,
                       coords, cidx, out);
}

// Round 2
// 131.020 us; speedup vs baseline: 1.0004x; 1.0004x over previous
//
#include <hip/hip_runtime.h>
#include <math.h>

#define kB 4
#define kM 4096
#define kN (kB * kM)
#define kPadF -999.0f
#define kPadI -999

// ---------------------------------------------------------------------------
// Kernel 1: per-atom outputs — dihedral (col 0), partners (cols 2..7) —
// plus pre-gather of (x, y, z, 0.5*|r|^2) into ws for the nbr kernel.
// Grid: 256 blocks x 64 threads (one wave/block, spread over all CUs).
// ---------------------------------------------------------------------------
__global__ __launch_bounds__(64)
void per_atom_kernel(const float* __restrict__ coords,   // (B,M,3)
                     const int*   __restrict__ cidx,     // (N,)
                     const int*   __restrict__ partners, // (N,2)
                     const int*   __restrict__ aidx,     // (N,4)
                     float*       __restrict__ out,      // (N,8)
                     float4*      __restrict__ ws)       // (N,) gathered
{
    int i = blockIdx.x * 64 + threadIdx.x;
    if (i >= kN) return;
    int b = i >> 12;  // atom_batch = i // M, M = 4096

    // ---- pre-gather for nbr kernel (issue first, independent) ----
    {
        int gc = cidx[i];
        const float* s = coords + (size_t)(b * kM + gc) * 3;
        float x = s[0], y = s[1], z = s[2];
        ws[i] = make_float4(x, y, z, 0.5f * (x * x + y * y + z * z));
    }

    // ---- partners (cols 2..7) ----
    float o2, o3, o4, o5, o6, o7;
    int p0 = partners[2 * i + 0];
    int p1 = partners[2 * i + 1];
    if (p0 == kPadI) { o2 = o3 = o4 = kPadF; }
    else {
        const float* s = coords + (size_t)(b * kM + p0) * 3;
        o2 = s[0]; o3 = s[1]; o4 = s[2];
    }
    if (p1 == kPadI) { o5 = o6 = o7 = kPadF; }
    else {
        const float* s = coords + (size_t)(b * kM + p1) * 3;
        o5 = s[0]; o6 = s[1]; o7 = s[2];
    }

    // ---- dihedral (col 0) ----
    int4 a = *reinterpret_cast<const int4*>(aidx + 4 * i);
    float ang = kPadF;
    if (a.x != kPadI && a.y != kPadI && a.z != kPadI && a.w != kPadI) {
        int ai[4] = {a.x, a.y, a.z, a.w};
        float P[4][3];
        #pragma unroll
        for (int k = 0; k < 4; ++k) {
            int g  = ai[k];
            int gb = g >> 12;
            int gc = cidx[g];
            const float* s = coords + (size_t)(gb * kM + gc) * 3;
            P[k][0] = s[0]; P[k][1] = s[1]; P[k][2] = s[2];
        }
        float b1x = P[1][0] - P[0][0], b1y = P[1][1] - P[0][1], b1z = P[1][2] - P[0][2];
        float b2x = P[2][0] - P[1][0], b2y = P[2][1] - P[1][1], b2z = P[2][2] - P[1][2];
        float b3x = P[3][0] - P[2][0], b3y = P[3][1] - P[2][1], b3z = P[3][2] - P[2][2];
        float n1x = b1y * b2z - b1z * b2y;
        float n1y = b1z * b2x - b1x * b2z;
        float n1z = b1x * b2y - b1y * b2x;
        float n2x = b2y * b3z - b2z * b3y;
        float n2y = b2z * b3x - b2x * b3z;
        float n2z = b2x * b3y - b2y * b3x;
        float nb2 = sqrtf(b2x * b2x + b2y * b2y + b2z * b2z) + 1e-12f;
        float inv = 1.0f / nb2;
        float ux = b2x * inv, uy = b2y * inv, uz = b2z * inv;
        float m1x = n1y * uz - n1z * uy;
        float m1y = n1z * ux - n1x * uz;
        float m1z = n1x * uy - n1y * ux;
        float x = n1x * n2x + n1y * n2y + n1z * n2z;
        float y = m1x * n2x + m1y * n2y + m1z * n2z;
        ang = atan2f(y, x);
    }

    // two vector stores; col 1 placeholder 0 is overwritten by nbr_kernel
    float4* o = reinterpret_cast<float4*>(out + (size_t)i * 8);
    o[0] = make_float4(ang, 0.0f, o2, o3);
    o[1] = make_float4(o4, o5, o6, o7);
}

// ---------------------------------------------------------------------------
// Kernel 2: masked pairwise-distance row sums (col 1), from pre-gathered ws.
// Grid: B*M/16 = 1024 blocks x 256 threads. 16 rows/block, 16 threads/row.
// Common path: 5 VALU/pair (dot >= thr prefilter); exact sqrt path is rare.
// ---------------------------------------------------------------------------
__global__ __launch_bounds__(256)
void nbr_kernel(const float4* __restrict__ ws,  // (B*M,) x,y,z,0.5*sq
                float*        __restrict__ out) // (N,8)
{
    int blk  = blockIdx.x;
    int b    = blk >> 8;              // 256 blocks per batch
    int row0 = (blk & 255) << 4;      // 16 rows per block
    int r    = row0 + (threadIdx.x >> 4);
    int sub  = threadIdx.x & 15;

    const float4* base = ws + (size_t)b * kM;
    float4 ci = base[r];
    float  a  = ci.w - 24.501f;       // margin makes prefilter conservative

    float sum = 0.0f;
    #pragma unroll 4
    for (int k = 0; k < kM / 16; ++k) {
        float4 c  = base[k * 16 + sub];            // 256B contiguous per wave
        float dot = ci.x * c.x + ci.y * c.y + ci.z * c.z;
        float thr = a + c.w;
        if (dot >= thr) {                          // d2 <= 49.002 superset
            // exact reference formula for included pairs
            float d2   = 2.0f * ci.w + 2.0f * c.w - 2.0f * dot;
            float dist = sqrtf(fmaxf(d2, 0.0f) + 1e-12f);
            if (dist <= 7.0f) sum += dist;
        }
    }
    // reduce across the 16 lanes that share a row
    sum += __shfl_xor(sum, 1);
    sum += __shfl_xor(sum, 2);
    sum += __shfl_xor(sum, 4);
    sum += __shfl_xor(sum, 8);
    if (sub == 0) {
        out[(size_t)(b * kM + r) * 8 + 1] = (ci.x != kPadF) ? sum : 0.0f;
    }
}

// ---------------------------------------------------------------------------
// Fallback (ws too small): self-contained v1-style nbr kernel with LDS staging.
// ---------------------------------------------------------------------------
__global__ __launch_bounds__(256)
void nbr_kernel_lds(const float* __restrict__ coords,
                    const int*   __restrict__ cidx,
                    float*       __restrict__ out)
{
    __shared__ float4 sc[kM];
    int b    = blockIdx.x >> 6;
    int row0 = (blockIdx.x & 63) << 6;
    for (int j = threadIdx.x; j < kM; j += 256) {
        int idx = cidx[b * kM + j];
        const float* s = coords + (size_t)(b * kM + idx) * 3;
        float x = s[0], y = s[1], z = s[2];
        sc[j] = make_float4(x, y, z, 0.5f * (x * x + y * y + z * z));
    }
    __syncthreads();
    int r   = row0 + (threadIdx.x >> 2);
    int sub = threadIdx.x & 3;
    float4 ci = sc[r];
    float  a  = ci.w - 24.501f;
    float sum = 0.0f;
    #pragma unroll 4
    for (int jj = 0; jj < kM / 4; ++jj) {
        float4 c  = sc[4 * jj + sub];
        float dot = ci.x * c.x + ci.y * c.y + ci.z * c.z;
        float thr = a + c.w;
        if (dot >= thr) {
            float d2   = 2.0f * ci.w + 2.0f * c.w - 2.0f * dot;
            float dist = sqrtf(fmaxf(d2, 0.0f) + 1e-12f);
            if (dist <= 7.0f) sum += dist;
        }
    }
    sum += __shfl_xor(sum, 1);
    sum += __shfl_xor(sum, 2);
    if (sub == 0)
        out[(size_t)(b * kM + r) * 8 + 1] = (ci.x != kPadF) ? sum : 0.0f;
}

// ---------------------------------------------------------------------------
extern "C" void kernel_launch(void* const* d_in, const int* in_sizes, int n_in,
                              void* d_out, int out_size, void* d_ws, size_t ws_size,
                              hipStream_t stream) {
    const float* coords   = (const float*)d_in[0];
    const int*   cidx     = (const int*)d_in[2];
    const int*   partners = (const int*)d_in[3];
    const int*   aidx     = (const int*)d_in[4];
    float*       out      = (float*)d_out;
    float4*      ws       = (float4*)d_ws;

    hipLaunchKernelGGL(per_atom_kernel, dim3(kN / 64), dim3(64), 0, stream,
                       coords, cidx, partners, aidx, out, ws);

    if (ws_size >= (size_t)kN * sizeof(float4)) {
        hipLaunchKernelGGL(nbr_kernel, dim3(kB * (kM / 16)), dim3(256), 0, stream,
                           ws, out);
    } else {
        hipLaunchKernelGGL(nbr_kernel_lds, dim3(kB * 64), dim3(256), 0, stream,
                           coords, cidx, out);
    }
}

// Round 3
// 100.513 us; speedup vs baseline: 1.3040x; 1.3035x over previous
//
#include <hip/hip_runtime.h>
#include <math.h>

#define kB 4
#define kM 4096
#define kN (kB * kM)
#define kPadF -999.0f
#define kPadI -999

// ---------------------------------------------------------------------------
// Kernel 1: per-atom outputs — dihedral (col 0), partners (cols 2..7) —
// plus pre-gather of (x, y, z, 0.5*|r|^2) into ws for the nbr kernel.
// Also zero-initializes out col 1 (accumulated atomically by nbr_kernel).
// ---------------------------------------------------------------------------
__global__ __launch_bounds__(64)
void per_atom_kernel(const float* __restrict__ coords,   // (B,M,3)
                     const int*   __restrict__ cidx,     // (N,)
                     const int*   __restrict__ partners, // (N,2)
                     const int*   __restrict__ aidx,     // (N,4)
                     float*       __restrict__ out,      // (N,8)
                     float4*      __restrict__ ws)       // (N,) gathered
{
    int i = blockIdx.x * 64 + threadIdx.x;
    if (i >= kN) return;
    int b = i >> 12;  // atom_batch = i // M, M = 4096

    // ---- pre-gather for nbr kernel: x, y, z, hw = 0.5*(x^2+y^2+z^2) ----
    {
        int gc = cidx[i];
        const float* s = coords + (size_t)(b * kM + gc) * 3;
        float x = s[0], y = s[1], z = s[2];
        ws[i] = make_float4(x, y, z, 0.5f * (x * x + y * y + z * z));
    }

    // ---- partners (cols 2..7) ----
    float o2, o3, o4, o5, o6, o7;
    int p0 = partners[2 * i + 0];
    int p1 = partners[2 * i + 1];
    if (p0 == kPadI) { o2 = o3 = o4 = kPadF; }
    else {
        const float* s = coords + (size_t)(b * kM + p0) * 3;
        o2 = s[0]; o3 = s[1]; o4 = s[2];
    }
    if (p1 == kPadI) { o5 = o6 = o7 = kPadF; }
    else {
        const float* s = coords + (size_t)(b * kM + p1) * 3;
        o5 = s[0]; o6 = s[1]; o7 = s[2];
    }

    // ---- dihedral (col 0) ----
    int4 a = *reinterpret_cast<const int4*>(aidx + 4 * i);
    float ang = kPadF;
    if (a.x != kPadI && a.y != kPadI && a.z != kPadI && a.w != kPadI) {
        int ai[4] = {a.x, a.y, a.z, a.w};
        float P[4][3];
        #pragma unroll
        for (int k = 0; k < 4; ++k) {
            int g  = ai[k];
            int gb = g >> 12;
            int gc = cidx[g];
            const float* s = coords + (size_t)(gb * kM + gc) * 3;
            P[k][0] = s[0]; P[k][1] = s[1]; P[k][2] = s[2];
        }
        float b1x = P[1][0] - P[0][0], b1y = P[1][1] - P[0][1], b1z = P[1][2] - P[0][2];
        float b2x = P[2][0] - P[1][0], b2y = P[2][1] - P[1][1], b2z = P[2][2] - P[1][2];
        float b3x = P[3][0] - P[2][0], b3y = P[3][1] - P[2][1], b3z = P[3][2] - P[2][2];
        float n1x = b1y * b2z - b1z * b2y;
        float n1y = b1z * b2x - b1x * b2z;
        float n1z = b1x * b2y - b1y * b2x;
        float n2x = b2y * b3z - b2z * b3y;
        float n2y = b2z * b3x - b2x * b3z;
        float n2z = b2x * b3y - b2y * b3x;
        float nb2 = sqrtf(b2x * b2x + b2y * b2y + b2z * b2z) + 1e-12f;
        float inv = 1.0f / nb2;
        float ux = b2x * inv, uy = b2y * inv, uz = b2z * inv;
        float m1x = n1y * uz - n1z * uy;
        float m1y = n1z * ux - n1x * uz;
        float m1z = n1x * uy - n1y * ux;
        float x = n1x * n2x + n1y * n2y + n1z * n2z;
        float y = m1x * n2x + m1y * n2y + m1z * n2z;
        ang = atan2f(y, x);
    }

    float4* o = reinterpret_cast<float4*>(out + (size_t)i * 8);
    o[0] = make_float4(ang, 0.0f, o2, o3);   // col 1 = 0, accumulated later
    o[1] = make_float4(o4, o5, o6, o7);
}

// ---------------------------------------------------------------------------
// Kernel 2: masked pairwise-distance row sums (col 1).
// 512 blocks = 16 row-blocks (1024 rows) x 32 col-chunks (128 cols).
// Each thread owns 4 rows in registers; columns broadcast from LDS.
// Common path 5 VALU/pair; d2<=51 superset prefilter; atomicAdd partials.
// ---------------------------------------------------------------------------
__global__ __launch_bounds__(256)
void nbr_kernel(const float4* __restrict__ ws,  // (N,) x,y,z,0.5*sq
                float*        __restrict__ out) // (N,8)
{
    __shared__ float4 sc[128];

    int rowBlk = blockIdx.x >> 5;            // 0..15  (1024 rows each)
    int colChk = blockIdx.x & 31;            // 0..31  (128 cols each)
    int row0   = rowBlk << 10;
    int b      = rowBlk >> 2;                // 1024*4 = 4096 rows per batch
    int col0   = colChk << 7;

    int tid = threadIdx.x;
    if (tid < 128) sc[tid] = ws[(size_t)b * kM + col0 + tid];
    __syncthreads();

    // 4 rows per thread: row0 + tid + k*256
    float rx[4], ry[4], rz[4], rhw[4], rA[4], sum[4];
    bool  rv[4];
    #pragma unroll
    for (int k = 0; k < 4; ++k) {
        float4 ci = ws[row0 + tid + (k << 8)];
        rx[k] = ci.x; ry[k] = ci.y; rz[k] = ci.z; rhw[k] = ci.w;
        rA[k] = ci.w - 25.5f;                 // prefilter: dot >= rA + c.w  (d2 <= 51)
        rv[k] = (ci.x != kPadF);
        sum[k] = 0.0f;
    }

    #pragma unroll 2
    for (int j = 0; j < 128; ++j) {
        float4 c = sc[j];                     // wave-uniform -> LDS broadcast
        #pragma unroll
        for (int k = 0; k < 4; ++k) {
            float dot = rx[k] * c.x + ry[k] * c.y + rz[k] * c.z;
            if (dot >= rA[k] + c.w) {         // conservative superset of d2<=49
                float d2   = 2.0f * rhw[k] + 2.0f * c.w - 2.0f * dot;  // == sqi+sqj-2dot
                float dist = sqrtf(fmaxf(d2, 0.0f) + 1e-12f);
                if (dist <= 7.0f) sum[k] += dist;
            }
        }
    }

    #pragma unroll
    for (int k = 0; k < 4; ++k) {
        if (rv[k] && sum[k] != 0.0f) {
            atomicAdd(out + (size_t)(row0 + tid + (k << 8)) * 8 + 1, sum[k]);
        }
    }
}

// ---------------------------------------------------------------------------
// Fallback (ws too small): self-contained nbr kernel with LDS staging.
// ---------------------------------------------------------------------------
__global__ __launch_bounds__(256)
void nbr_kernel_lds(const float* __restrict__ coords,
                    const int*   __restrict__ cidx,
                    float*       __restrict__ out)
{
    __shared__ float4 sc[kM];
    int b    = blockIdx.x >> 6;
    int row0 = (blockIdx.x & 63) << 6;
    for (int j = threadIdx.x; j < kM; j += 256) {
        int idx = cidx[b * kM + j];
        const float* s = coords + (size_t)(b * kM + idx) * 3;
        float x = s[0], y = s[1], z = s[2];
        sc[j] = make_float4(x, y, z, 0.5f * (x * x + y * y + z * z));
    }
    __syncthreads();
    int r   = row0 + (threadIdx.x >> 2);
    int sub = threadIdx.x & 3;
    float4 ci = sc[r];
    float  a  = ci.w - 25.5f;
    float sum = 0.0f;
    for (int jj = 0; jj < kM / 4; ++jj) {
        float4 c  = sc[4 * jj + sub];
        float dot = ci.x * c.x + ci.y * c.y + ci.z * c.z;
        if (dot >= a + c.w) {
            float d2   = 2.0f * ci.w + 2.0f * c.w - 2.0f * dot;
            float dist = sqrtf(fmaxf(d2, 0.0f) + 1e-12f);
            if (dist <= 7.0f) sum += dist;
        }
    }
    sum += __shfl_xor(sum, 1);
    sum += __shfl_xor(sum, 2);
    if (sub == 0)
        out[(size_t)(b * kM + r) * 8 + 1] = (ci.x != kPadF) ? sum : 0.0f;
}

// ---------------------------------------------------------------------------
extern "C" void kernel_launch(void* const* d_in, const int* in_sizes, int n_in,
                              void* d_out, int out_size, void* d_ws, size_t ws_size,
                              hipStream_t stream) {
    const float* coords   = (const float*)d_in[0];
    const int*   cidx     = (const int*)d_in[2];
    const int*   partners = (const int*)d_in[3];
    const int*   aidx     = (const int*)d_in[4];
    float*       out      = (float*)d_out;
    float4*      ws       = (float4*)d_ws;

    hipLaunchKernelGGL(per_atom_kernel, dim3(kN / 64), dim3(64), 0, stream,
                       coords, cidx, partners, aidx, out, ws);

    if (ws_size >= (size_t)kN * sizeof(float4)) {
        hipLaunchKernelGGL(nbr_kernel, dim3(512), dim3(256), 0, stream,
                           ws, out);
    } else {
        hipLaunchKernelGGL(nbr_kernel_lds, dim3(kB * 64), dim3(256), 0, stream,
                           coords, cidx, out);
    }
}

// Round 4
// 86.604 us; speedup vs baseline: 1.5134x; 1.1606x over previous
//
#include <hip/hip_runtime.h>
#include <math.h>

#define kB 4
#define kM 4096
#define kN (kB * kM)
#define kPadF -999.0f
#define kPadI -999

// ---------------------------------------------------------------------------
// Kernel 1: per-atom outputs — dihedral (col 0), partners (cols 2..7) —
// plus pre-gather of (x, y, z, |r|^2) into ws for the nbr kernel.
// ws.w is the FULL squared norm so nbr's d2 bit-matches the R1 formula
// (sq_i + sq_j - 2*dot), which measured absmax 0.5 vs the np reference.
// ---------------------------------------------------------------------------
__global__ __launch_bounds__(64)
void per_atom_kernel(const float* __restrict__ coords,   // (B,M,3)
                     const int*   __restrict__ cidx,     // (N,)
                     const int*   __restrict__ partners, // (N,2)
                     const int*   __restrict__ aidx,     // (N,4)
                     float*       __restrict__ out,      // (N,8)
                     float4*      __restrict__ ws)       // (N,) gathered
{
    int i = blockIdx.x * 64 + threadIdx.x;
    if (i >= kN) return;
    int b = i >> 12;  // atom_batch = i // M, M = 4096

    // ---- pre-gather for nbr kernel: x, y, z, sq = x^2+y^2+z^2 ----
    {
        int gc = cidx[i];
        const float* s = coords + (size_t)(b * kM + gc) * 3;
        float x = s[0], y = s[1], z = s[2];
        ws[i] = make_float4(x, y, z, x * x + y * y + z * z);
    }

    // ---- partners (cols 2..7) ----
    float o2, o3, o4, o5, o6, o7;
    int p0 = partners[2 * i + 0];
    int p1 = partners[2 * i + 1];
    if (p0 == kPadI) { o2 = o3 = o4 = kPadF; }
    else {
        const float* s = coords + (size_t)(b * kM + p0) * 3;
        o2 = s[0]; o3 = s[1]; o4 = s[2];
    }
    if (p1 == kPadI) { o5 = o6 = o7 = kPadF; }
    else {
        const float* s = coords + (size_t)(b * kM + p1) * 3;
        o5 = s[0]; o6 = s[1]; o7 = s[2];
    }

    // ---- dihedral (col 0) ----
    int4 a = *reinterpret_cast<const int4*>(aidx + 4 * i);
    float ang = kPadF;
    if (a.x != kPadI && a.y != kPadI && a.z != kPadI && a.w != kPadI) {
        int ai[4] = {a.x, a.y, a.z, a.w};
        float P[4][3];
        #pragma unroll
        for (int k = 0; k < 4; ++k) {
            int g  = ai[k];
            int gb = g >> 12;
            int gc = cidx[g];
            const float* s = coords + (size_t)(gb * kM + gc) * 3;
            P[k][0] = s[0]; P[k][1] = s[1]; P[k][2] = s[2];
        }
        float b1x = P[1][0] - P[0][0], b1y = P[1][1] - P[0][1], b1z = P[1][2] - P[0][2];
        float b2x = P[2][0] - P[1][0], b2y = P[2][1] - P[1][1], b2z = P[2][2] - P[1][2];
        float b3x = P[3][0] - P[2][0], b3y = P[3][1] - P[2][1], b3z = P[3][2] - P[2][2];
        float n1x = b1y * b2z - b1z * b2y;
        float n1y = b1z * b2x - b1x * b2z;
        float n1z = b1x * b2y - b1y * b2x;
        float n2x = b2y * b3z - b2z * b3y;
        float n2y = b2z * b3x - b2x * b3z;
        float n2z = b2x * b3y - b2y * b3x;
        float nb2 = sqrtf(b2x * b2x + b2y * b2y + b2z * b2z) + 1e-12f;
        float inv = 1.0f / nb2;
        float ux = b2x * inv, uy = b2y * inv, uz = b2z * inv;
        float m1x = n1y * uz - n1z * uy;
        float m1y = n1z * ux - n1x * uz;
        float m1z = n1x * uy - n1y * ux;
        float x = n1x * n2x + n1y * n2y + n1z * n2z;
        float y = m1x * n2x + m1y * n2y + m1z * n2z;
        ang = atan2f(y, x);
    }

    float4* o = reinterpret_cast<float4*>(out + (size_t)i * 8);
    o[0] = make_float4(ang, 0.0f, o2, o3);   // col 1 = 0, accumulated later
    o[1] = make_float4(o4, o5, o6, o7);
}

// ---------------------------------------------------------------------------
// Kernel 2: masked pairwise-distance row sums (col 1).
// Grid 2048 = 32 row-blocks (512 rows) x 64 col-chunks (64 cols).
// 8 blocks/CU, 32 waves/CU. 2 rows/thread in registers; 64 columns in LDS,
// read in explicit 4-wide batches (4 ds_read_b128 in flight per wave).
// Prefilter: 2*dot >= sq_i + sq_j - 51  (d2 <= 51 superset of ref d2 <= 49);
// rare path recomputes d2 with the R1-exact expression.
// ---------------------------------------------------------------------------
__global__ __launch_bounds__(256)
void nbr_kernel(const float4* __restrict__ ws,  // (N,) x,y,z,sq
                float*        __restrict__ out) // (N,8)
{
    __shared__ float4 sc[64];

    int rowBlk = blockIdx.x >> 6;     // 0..31  (512 rows each)
    int colChk = blockIdx.x & 63;     // 0..63  (64 cols each)
    int row0   = rowBlk << 9;
    int b      = rowBlk >> 3;         // 8 row-blocks per batch
    int col0   = colChk << 6;

    int tid = threadIdx.x;
    if (tid < 64) sc[tid] = ws[(size_t)b * kM + col0 + tid];
    __syncthreads();

    int r0 = row0 + tid;              // this thread's rows: r0, r0+256
    float4 ci0 = ws[r0];
    float4 ci1 = ws[r0 + 256];
    float  rA0 = 0.5f * ci0.w - 25.5f;   // dot >= rA + 0.5*sq_j
    float  rA1 = 0.5f * ci1.w - 25.5f;
    float  sum0 = 0.0f, sum1 = 0.0f;

    for (int j = 0; j < 64; j += 4) {
        float4 cc[4];
        cc[0] = sc[j + 0]; cc[1] = sc[j + 1];
        cc[2] = sc[j + 2]; cc[3] = sc[j + 3];
        #pragma unroll
        for (int u = 0; u < 4; ++u) {
            float4 c  = cc[u];
            float  ch = 0.5f * c.w;
            float dot0 = ci0.x * c.x + ci0.y * c.y + ci0.z * c.z;
            float dot1 = ci1.x * c.x + ci1.y * c.y + ci1.z * c.z;
            if (dot0 >= rA0 + ch) {
                float d2   = ci0.w + c.w - 2.0f * dot0;     // R1-exact
                float dist = sqrtf(fmaxf(d2, 0.0f) + 1e-12f);
                if (dist <= 7.0f) sum0 += dist;
            }
            if (dot1 >= rA1 + ch) {
                float d2   = ci1.w + c.w - 2.0f * dot1;
                float dist = sqrtf(fmaxf(d2, 0.0f) + 1e-12f);
                if (dist <= 7.0f) sum1 += dist;
            }
        }
    }

    if (ci0.x != kPadF && sum0 != 0.0f)
        atomicAdd(out + (size_t)r0 * 8 + 1, sum0);
    if (ci1.x != kPadF && sum1 != 0.0f)
        atomicAdd(out + (size_t)(r0 + 256) * 8 + 1, sum1);
}

// ---------------------------------------------------------------------------
// Fallback (ws too small): self-contained nbr kernel with LDS staging.
// ---------------------------------------------------------------------------
__global__ __launch_bounds__(256)
void nbr_kernel_lds(const float* __restrict__ coords,
                    const int*   __restrict__ cidx,
                    float*       __restrict__ out)
{
    __shared__ float4 sc[kM];
    int b    = blockIdx.x >> 6;
    int row0 = (blockIdx.x & 63) << 6;
    for (int j = threadIdx.x; j < kM; j += 256) {
        int idx = cidx[b * kM + j];
        const float* s = coords + (size_t)(b * kM + idx) * 3;
        float x = s[0], y = s[1], z = s[2];
        sc[j] = make_float4(x, y, z, x * x + y * y + z * z);
    }
    __syncthreads();
    int r   = row0 + (threadIdx.x >> 2);
    int sub = threadIdx.x & 3;
    float4 ci = sc[r];
    float  a  = 0.5f * ci.w - 25.5f;
    float sum = 0.0f;
    for (int jj = 0; jj < kM / 4; ++jj) {
        float4 c  = sc[4 * jj + sub];
        float dot = ci.x * c.x + ci.y * c.y + ci.z * c.z;
        if (dot >= a + 0.5f * c.w) {
            float d2   = ci.w + c.w - 2.0f * dot;
            float dist = sqrtf(fmaxf(d2, 0.0f) + 1e-12f);
            if (dist <= 7.0f) sum += dist;
        }
    }
    sum += __shfl_xor(sum, 1);
    sum += __shfl_xor(sum, 2);
    if (sub == 0)
        out[(size_t)(b * kM + r) * 8 + 1] = (ci.x != kPadF) ? sum : 0.0f;
}

// ---------------------------------------------------------------------------
extern "C" void kernel_launch(void* const* d_in, const int* in_sizes, int n_in,
                              void* d_out, int out_size, void* d_ws, size_t ws_size,
                              hipStream_t stream) {
    const float* coords   = (const float*)d_in[0];
    const int*   cidx     = (const int*)d_in[2];
    const int*   partners = (const int*)d_in[3];
    const int*   aidx     = (const int*)d_in[4];
    float*       out      = (float*)d_out;
    float4*      ws       = (float4*)d_ws;

    hipLaunchKernelGGL(per_atom_kernel, dim3(kN / 64), dim3(64), 0, stream,
                       coords, cidx, partners, aidx, out, ws);

    if (ws_size >= (size_t)kN * sizeof(float4)) {
        hipLaunchKernelGGL(nbr_kernel, dim3(2048), dim3(256), 0, stream,
                           ws, out);
    } else {
        hipLaunchKernelGGL(nbr_kernel_lds, dim3(kB * 64), dim3(256), 0, stream,
                           coords, cidx, out);
    }
}